// Round 2
// baseline (674.587 us; speedup 1.0000x reference)
//
#include <hip/hip_runtime.h>
#include <stdint.h>

#define N_ENT 100000
#define D1    200
#define BATCH 1024
#define KPAD  224            // 200 padded to 7*32
#define NTILES 782           // 782*128 = 100096 >= N_ENT

typedef unsigned short ushort_t;
typedef __attribute__((ext_vector_type(8))) short short8;
typedef __attribute__((ext_vector_type(4))) float f32x4;

__constant__ int c_perm[11] = {8, 0, 3, 9, 4, 5, 6, 7, 1, 10, 2};

__device__ __forceinline__ unsigned short f2bf(float f) {
    unsigned int u = __float_as_uint(f);
    unsigned int r = (u + 0x7fffu + ((u >> 16) & 1u)) >> 16;
    return (unsigned short)r;
}

__device__ __forceinline__ int sym_idx(int a, int b) {
    int i = a < b ? a : b;
    int j = a < b ? b : a;
    return i * D1 - (i * (i - 1)) / 2 + (j - i);
}
// requires i < j
__device__ __forceinline__ int asym_idx(int i, int j) {
    return i * D1 - (i * (i + 1)) / 2 + (j - i - 1);
}

// ---------------- M[rel] = sum_i R[rel,i] * W[i] (11 x 200 x 200) ----------------
__global__ void build_M(const float* __restrict__ R1, const float* __restrict__ R2,
                        const float* __restrict__ R3, const float* __restrict__ W1,
                        const float* __restrict__ W2, const float* __restrict__ W3,
                        float* __restrict__ M) {
    int rel = blockIdx.y;
    int e = blockIdx.x * 256 + threadIdx.x;
    if (e >= D1 * D1) return;
    int j = e / D1;
    int k = e - j * D1;
    float acc = 0.f;
    if (rel < 3) {
        int si = sym_idx(j, k);
        #pragma unroll 6
        for (int i = 0; i < 30; i++) acc += R1[rel * 30 + i] * W1[i * 20100 + si];
    } else if (rel < 8) {
        if (j != k) {
            int ai = (j < k) ? asym_idx(j, k) : asym_idx(k, j);
            float s = (j < k) ? 1.f : -1.f;
            #pragma unroll 6
            for (int i = 0; i < 30; i++) acc += R2[(rel - 3) * 30 + i] * s * W2[i * 19900 + ai];
        }
    } else {
        const float* r3 = R3 + (rel - 8) * 80;
        int si = sym_idx(j, k);
        #pragma unroll 6
        for (int i = 0; i < 30; i++) acc += r3[i] * W1[i * 20100 + si];
        if (j != k) {
            int ai = (j < k) ? asym_idx(j, k) : asym_idx(k, j);
            float s = (j < k) ? 1.f : -1.f;
            #pragma unroll 6
            for (int i = 0; i < 30; i++) acc += r3[30 + i] * s * W2[i * 19900 + ai];
        }
        #pragma unroll 5
        for (int i = 0; i < 20; i++) acc += r3[60 + i] * W3[i * 40000 + e];
    }
    M[rel * 40000 + e] = acc;
}

// ---------------- batchnorm stats -> scale/shift ----------------
__global__ void bn0_stats(const float* __restrict__ E, const int* __restrict__ e1_idx,
                          const float* __restrict__ gamma, const float* __restrict__ beta,
                          float* __restrict__ scale, float* __restrict__ shift) {
    int f = blockIdx.x;
    int tid = threadIdx.x;
    float s = 0.f, sq = 0.f;
    for (int b = tid; b < BATCH; b += 256) {
        float v = E[e1_idx[b] * D1 + f];
        s += v; sq += v * v;
    }
    __shared__ float ls[256], lq[256];
    ls[tid] = s; lq[tid] = sq;
    __syncthreads();
    for (int off = 128; off > 0; off >>= 1) {
        if (tid < off) { ls[tid] += ls[tid + off]; lq[tid] += lq[tid + off]; }
        __syncthreads();
    }
    if (tid == 0) {
        float m = ls[0] * (1.f / BATCH);
        float var = lq[0] * (1.f / BATCH) - m * m;
        float rstd = rsqrtf(var + 1e-5f);
        scale[f] = rstd * gamma[f];
        shift[f] = beta[f] - m * rstd * gamma[f];
    }
}

__global__ void bn1_stats(const float* __restrict__ y,
                          const float* __restrict__ gamma, const float* __restrict__ beta,
                          float* __restrict__ scale, float* __restrict__ shift) {
    int f = blockIdx.x;
    int tid = threadIdx.x;
    float s = 0.f, sq = 0.f;
    for (int b = tid; b < BATCH; b += 256) {
        float v = y[b * D1 + f];
        s += v; sq += v * v;
    }
    __shared__ float ls[256], lq[256];
    ls[tid] = s; lq[tid] = sq;
    __syncthreads();
    for (int off = 128; off > 0; off >>= 1) {
        if (tid < off) { ls[tid] += ls[tid + off]; lq[tid] += lq[tid + off]; }
        __syncthreads();
    }
    if (tid == 0) {
        float m = ls[0] * (1.f / BATCH);
        float var = lq[0] * (1.f / BATCH) - m * m;
        float rstd = rsqrtf(var + 1e-5f);
        scale[f] = rstd * gamma[f];
        shift[f] = beta[f] - m * rstd * gamma[f];
    }
}

// ---------------- y[b,k] = sum_j bn0(E[e1[b]])[j] * M[rel_b][j][k] ----------------
__global__ void xw_kernel(const float* __restrict__ E, const int* __restrict__ e1_idx,
                          const int* __restrict__ r_idx,
                          const float* __restrict__ scale0, const float* __restrict__ shift0,
                          const float* __restrict__ M, float* __restrict__ y) {
    int b = blockIdx.x;
    int tid = threadIdx.x;
    __shared__ float xs[D1];
    __shared__ int s_rel;
    if (tid == 0) s_rel = c_perm[r_idx[b]];
    int e1 = e1_idx[b];
    if (tid < D1) xs[tid] = E[e1 * D1 + tid] * scale0[tid] + shift0[tid];
    __syncthreads();
    if (tid < D1) {
        const float* Mr = M + s_rel * 40000;
        float acc = 0.f;
        #pragma unroll 8
        for (int j = 0; j < D1; j++) acc += xs[j] * Mr[j * D1 + tid];
        y[b * D1 + tid] = acc;
    }
}

// ---------------- fused scores GEMM ----------------
// out[b,n] = sigmoid( sum_k bn1(y)[b,k] * E[n,k] )
// A tile staged from y (fp32) with bn1 scale/shift applied + bf16 convert in-reg.
// B tile staged from E (fp32) with bf16 convert in-reg.
__global__ __launch_bounds__(256) void gemm_score(const float* __restrict__ y,
                                                  const float* __restrict__ E,
                                                  const float* __restrict__ scale1,
                                                  const float* __restrict__ shift1,
                                                  float* __restrict__ out) {
    __shared__ ushort_t As[128 * 32];
    __shared__ ushort_t Bs[128 * 32];
    __shared__ float s_sc[KPAD], s_sh[KPAD];
    const int tid = threadIdx.x;
    const int wave = tid >> 6;
    const int lane = tid & 63;
    const int wm = wave >> 1, wn = wave & 1;
    const int quad = lane >> 4, l16 = lane & 15;
    const int tile_n = blockIdx.x * 128;
    const int tile_m = blockIdx.y * 128;

    const int srow = tid >> 2;   // 0..63
    const int sseg = tid & 3;    // 0..3

    if (tid < KPAD) {
        s_sc[tid] = (tid < D1) ? scale1[tid] : 0.f;
        s_sh[tid] = (tid < D1) ? shift1[tid] : 0.f;
    }
    __syncthreads();

    f32x4 acc[4][4];
    #pragma unroll
    for (int i = 0; i < 4; i++)
        #pragma unroll
        for (int j = 0; j < 4; j++) acc[i][j] = (f32x4){0.f, 0.f, 0.f, 0.f};

    for (int kb = 0; kb < KPAD; kb += 32) {
        const int k0 = kb + sseg * 8;
        const bool kin = (k0 < D1);   // k0 multiple of 8; k0<=192 -> all 8 cols valid
        #pragma unroll
        for (int rr = 0; rr < 2; rr++) {
            const int row = rr * 64 + srow;           // 0..127
            // ---- A: y row (always valid, tile_m+row < 1024) ----
            short8 ha;
            if (kin) {
                const float* p = y + (tile_m + row) * D1 + k0;
                #pragma unroll
                for (int j = 0; j < 8; j++) {
                    float x = p[j] * s_sc[k0 + j] + s_sh[k0 + j];
                    ha[j] = (short)f2bf(x);
                }
            } else {
                #pragma unroll
                for (int j = 0; j < 8; j++) ha[j] = 0;
            }
            *(short8*)&As[row * 32 + sseg * 8] = ha;
            // ---- B: E row (guard n < N_ENT) ----
            const int gn = tile_n + row;
            short8 hb;
            if (kin && gn < N_ENT) {
                const float* q = E + (size_t)gn * D1 + k0;
                #pragma unroll
                for (int j = 0; j < 8; j++) hb[j] = (short)f2bf(q[j]);
            } else {
                #pragma unroll
                for (int j = 0; j < 8; j++) hb[j] = 0;
            }
            *(short8*)&Bs[row * 32 + sseg * 8] = hb;
        }
        __syncthreads();

        short8 a_frag[4], b_frag[4];
        #pragma unroll
        for (int f = 0; f < 4; f++) {
            a_frag[f] = *(const short8*)&As[(wm * 64 + f * 16 + l16) * 32 + quad * 8];
            b_frag[f] = *(const short8*)&Bs[(wn * 64 + f * 16 + l16) * 32 + quad * 8];
        }
        #pragma unroll
        for (int fm = 0; fm < 4; fm++)
            #pragma unroll
            for (int fn = 0; fn < 4; fn++)
                acc[fm][fn] = __builtin_amdgcn_mfma_f32_16x16x32_bf16(
                    a_frag[fm], b_frag[fn], acc[fm][fn], 0, 0, 0);
        __syncthreads();
    }

    // epilogue: D layout col = lane&15, row = quad*4 + reg; nontemporal stores
    #pragma unroll
    for (int fm = 0; fm < 4; fm++) {
        int m = tile_m + wm * 64 + fm * 16 + quad * 4;
        #pragma unroll
        for (int fn = 0; fn < 4; fn++) {
            int n = tile_n + wn * 64 + fn * 16 + l16;
            if (n < N_ENT) {
                float* po = out + (size_t)m * N_ENT + n;
                #pragma unroll
                for (int r = 0; r < 4; r++) {
                    float v = acc[fm][fn][r];
                    float sg = 1.f / (1.f + __expf(-v));
                    __builtin_nontemporal_store(sg, po + (size_t)r * N_ENT);
                }
            }
        }
    }
}

extern "C" void kernel_launch(void* const* d_in, const int* in_sizes, int n_in,
                              void* d_out, int out_size, void* d_ws, size_t ws_size,
                              hipStream_t stream) {
    const float* E  = (const float*)d_in[0];
    const float* R1 = (const float*)d_in[1];
    const float* R2 = (const float*)d_in[2];
    const float* R3 = (const float*)d_in[3];
    const float* W1 = (const float*)d_in[4];
    const float* W2 = (const float*)d_in[5];
    const float* W3 = (const float*)d_in[6];
    const float* g0 = (const float*)d_in[7];
    const float* b0 = (const float*)d_in[8];
    const float* g1 = (const float*)d_in[9];
    const float* b1 = (const float*)d_in[10];
    const int* e1_idx = (const int*)d_in[11];
    const int* r_idx  = (const int*)d_in[12];
    float* out = (float*)d_out;

    char* ws = (char*)d_ws;
    float* M      = (float*)ws;                 // 11*40000*4 = 1,760,000 B
    float* scale0 = (float*)(ws + 1760000);
    float* shift0 = scale0 + D1;
    float* scale1 = shift0 + D1;
    float* shift1 = scale1 + D1;
    float* y      = shift1 + D1;                // BATCH*D1*4 = 819,200 B

    bn0_stats<<<D1, 256, 0, stream>>>(E, e1_idx, g0, b0, scale0, shift0);
    build_M<<<dim3((D1 * D1 + 255) / 256, 11), 256, 0, stream>>>(R1, R2, R3, W1, W2, W3, M);
    xw_kernel<<<BATCH, 256, 0, stream>>>(E, e1_idx, r_idx, scale0, shift0, M, y);
    bn1_stats<<<D1, 256, 0, stream>>>(y, g1, b1, scale1, shift1);
    gemm_score<<<dim3(NTILES, BATCH / 128), 256, 0, stream>>>(y, E, scale1, shift1, out);
}